// Round 1
// baseline (1371.707 us; speedup 1.0000x reference)
//
#include <hip/hip_runtime.h>
#include <hip/hip_bf16.h>

#define HID 512
#define NH  8
#define DD  64
#define GG  64
#define EPSF 1e-5f

typedef __attribute__((ext_vector_type(8))) short short8;
typedef __attribute__((ext_vector_type(4))) short short4v;
typedef __attribute__((ext_vector_type(4))) float floatx4;

__device__ __forceinline__ short f2bf(float f) {
    union { float f; unsigned u; } v; v.f = f;
    unsigned r = v.u + 0x7fffu + ((v.u >> 16) & 1u);
    return (short)(r >> 16);
}
__device__ __forceinline__ float bf2f(short s) {
    union { unsigned u; float f; } v;
    v.u = ((unsigned)(unsigned short)s) << 16;
    return v.f;
}

// ---------------------------------------------------------------------------
// fold1: Wcat (1024x512 bf16) = [Wfx ; temp[h] * (Ws @ Wx_head)]
//        bias_cat (1024 f32)  = [bfx ; temp[h] * (Ws @ bx_head + bs)]
// ---------------------------------------------------------------------------
__global__ void fold1_kernel(const float* __restrict__ Wx, const float* __restrict__ bx,
                             const float* __restrict__ Wfx, const float* __restrict__ bfx,
                             const float* __restrict__ Ws, const float* __restrict__ bs,
                             const float* __restrict__ temp,
                             short* __restrict__ Wcat, float* __restrict__ bias_cat) {
    int idx = blockIdx.x * 256 + threadIdx.x;   // 0 .. 1024*512-1
    int row = idx >> 9;
    int k = idx & 511;
    float val;
    if (row < 512) {
        val = Wfx[row * 512 + k];
        if (k == 0) bias_cat[row] = bfx[row];
    } else {
        int hg = row - 512;
        int h = hg >> 6, g = hg & 63;
        float t = temp[h];
        float s = 0.f;
        #pragma unroll 8
        for (int d = 0; d < 64; ++d) s += Ws[g * 64 + d] * Wx[(h * 64 + d) * 512 + k];
        val = s * t;
        if (k == 0) {
            float b = 0.f;
            for (int d = 0; d < 64; ++d) b += Ws[g * 64 + d] * bx[h * 64 + d];
            bias_cat[row] = (b + bs[g]) * t;
        }
    }
    Wcat[idx] = f2bf(val);
}

// ---------------------------------------------------------------------------
// gemm_bt: C(M x ncols) = A(M x K) @ B(ncols x K)^T + bias, bf16 MFMA
//   A_F32: A is f32 (converted to bf16 in staging); else A is bf16 (short)
//   OUT_F32: C stored f32; else bf16 (short)
// 128x128 block tile, 256 threads (4 waves in 2x2), 16x16x32 MFMA, 4x4/wave.
// grid: (ncols/128, ceil(M/128))
// ---------------------------------------------------------------------------
template <bool A_F32, bool OUT_F32>
__global__ __launch_bounds__(256, 2)
void gemm_bt(const void* __restrict__ Ap, int lda,
             const short* __restrict__ B,           // (ncols x K) bf16 row-major
             const float* __restrict__ bias,
             void* __restrict__ Cp, int ldc,
             int M, int K) {
    __shared__ short As[128 * 40];   // row stride 40 shorts (80 B) to break bank conflicts
    __shared__ short Bs[128 * 40];

    const int tid = threadIdx.x;
    const int wid = tid >> 6, lane = tid & 63;
    const int col0 = blockIdx.x * 128;
    const int row0 = blockIdx.y * 128;
    const int wm = (wid >> 1) * 64, wn = (wid & 1) * 64;
    const int lr = lane & 15, lq = lane >> 4;

    floatx4 acc[4][4];
    #pragma unroll
    for (int i = 0; i < 4; ++i)
        #pragma unroll
        for (int j = 0; j < 4; ++j) acc[i][j] = (floatx4)(0.f);

    for (int k0 = 0; k0 < K; k0 += 32) {
        if constexpr (A_F32) {
            const float* A = (const float*)Ap;
            #pragma unroll
            for (int it = 0; it < 4; ++it) {
                int c = tid + it * 256;          // 0..1023
                int r = c >> 3;                  // 0..127
                int kq = (c & 7) * 4;            // 0..28
                int gr = row0 + r;
                float4 v = make_float4(0.f, 0.f, 0.f, 0.f);
                if (gr < M) v = *(const float4*)(A + (size_t)gr * lda + k0 + kq);
                short4v hh;
                hh.x = f2bf(v.x); hh.y = f2bf(v.y); hh.z = f2bf(v.z); hh.w = f2bf(v.w);
                *(short4v*)&As[r * 40 + kq] = hh;
            }
        } else {
            const short* A = (const short*)Ap;
            #pragma unroll
            for (int it = 0; it < 2; ++it) {
                int c = tid + it * 256;          // 0..511
                int r = c >> 2;                  // 0..127
                int kq = (c & 3) * 8;            // 0,8,16,24
                int gr = row0 + r;
                short8 v = (short8)(0);
                if (gr < M) v = *(const short8*)(A + (size_t)gr * lda + k0 + kq);
                *(short8*)&As[r * 40 + kq] = v;
            }
        }
        #pragma unroll
        for (int it = 0; it < 2; ++it) {
            int c = tid + it * 256;
            int r = c >> 2;
            int kq = (c & 3) * 8;
            short8 v = *(const short8*)(B + (size_t)(col0 + r) * K + k0 + kq);
            *(short8*)&Bs[r * 40 + kq] = v;
        }
        __syncthreads();

        short8 af[4], bfr[4];
        #pragma unroll
        for (int i = 0; i < 4; ++i) af[i]  = *(const short8*)&As[(wm + i * 16 + lr) * 40 + lq * 8];
        #pragma unroll
        for (int j = 0; j < 4; ++j) bfr[j] = *(const short8*)&Bs[(wn + j * 16 + lr) * 40 + lq * 8];
        #pragma unroll
        for (int i = 0; i < 4; ++i)
            #pragma unroll
            for (int j = 0; j < 4; ++j)
                acc[i][j] = __builtin_amdgcn_mfma_f32_16x16x32_bf16(af[i], bfr[j], acc[i][j], 0, 0, 0);
        __syncthreads();
    }

    // epilogue: D[m][n]: col = lane&15, row = (lane>>4)*4 + reg  [measured m89/m91]
    #pragma unroll
    for (int i = 0; i < 4; ++i) {
        #pragma unroll
        for (int r = 0; r < 4; ++r) {
            int grow = row0 + wm + i * 16 + lq * 4 + r;
            if (grow >= M) continue;
            #pragma unroll
            for (int j = 0; j < 4; ++j) {
                int gcol = col0 + wn + j * 16 + lr;
                float v = acc[i][j][r] + bias[gcol];
                if constexpr (OUT_F32) ((float*)Cp)[(size_t)grow * ldc + gcol] = v;
                else                   ((short*)Cp)[(size_t)grow * ldc + gcol] = f2bf(v);
            }
        }
    }
}

// ---------------------------------------------------------------------------
// softmax over the 64-wide g-groups of mid[:, 512:1024], in place (bf16).
// temperature already folded into the logits. One thread per (n, h).
// ---------------------------------------------------------------------------
__global__ __launch_bounds__(256)
void softmax_kernel(short* __restrict__ mid, int NT) {
    int t = blockIdx.x * 256 + threadIdx.x;
    if (t >= NT) return;
    int n = t >> 3, h = t & 7;
    short* p = mid + (size_t)n * 1024 + 512 + h * 64;
    short8 v[8];
    float f[64];
    #pragma unroll
    for (int i = 0; i < 8; ++i) v[i] = *(const short8*)(p + i * 8);
    float mx = -1e30f;
    #pragma unroll
    for (int i = 0; i < 64; ++i) { f[i] = bf2f(((short*)v)[i]); mx = fmaxf(mx, f[i]); }
    float sum = 0.f;
    #pragma unroll
    for (int i = 0; i < 64; ++i) { f[i] = __expf(f[i] - mx); sum += f[i]; }
    float inv = 1.f / sum;
    #pragma unroll
    for (int i = 0; i < 64; ++i) ((short*)v)[i] = f2bf(f[i] * inv);
    #pragma unroll
    for (int i = 0; i < 8; ++i) *(short8*)(p + i * 8) = v[i];
}

// ---------------------------------------------------------------------------
// pooling: tok_raw[h,g,d] += sum_n w[n,h,g] * fx[n,h,d]; norm[h,g] += sum_n w
// grid (96, 8), 256 threads; thread owns a 4x4 (g,d) patch; atomics at end.
// ---------------------------------------------------------------------------
__global__ __launch_bounds__(256)
void pool_kernel(const short* __restrict__ mid, float* __restrict__ tok_raw,
                 float* __restrict__ norm, int N, int chunk) {
    int h = blockIdx.y;
    int n0 = blockIdx.x * chunk;
    int n1 = min(n0 + chunk, N);
    int tid = threadIdx.x;
    int gi = tid >> 4, di = tid & 15;
    __shared__ short ws_[16][64];
    __shared__ short fs_[16][64];
    float c[4][4] = {};
    float nrm[4] = {};
    for (int nb = n0; nb < n1; nb += 16) {
        int nrows = min(16, n1 - nb);
        {
            int r = tid >> 4;        // 0..15
            int seg = tid & 15;      // 0..15
            int n = nb + r;
            short8 v = (short8)(0);
            if (n < n1) {
                if (seg < 8) v = *(const short8*)(mid + (size_t)n * 1024 + 512 + h * 64 + seg * 8);
                else         v = *(const short8*)(mid + (size_t)n * 1024 + h * 64 + (seg - 8) * 8);
            }
            if (seg < 8) *(short8*)&ws_[r][seg * 8] = v;
            else         *(short8*)&fs_[r][(seg - 8) * 8] = v;
        }
        __syncthreads();
        for (int r = 0; r < nrows; ++r) {
            short4v a = *(const short4v*)&ws_[r][gi * 4];
            short4v b = *(const short4v*)&fs_[r][di * 4];
            float wv[4], fv[4];
            wv[0] = bf2f(a.x); wv[1] = bf2f(a.y); wv[2] = bf2f(a.z); wv[3] = bf2f(a.w);
            fv[0] = bf2f(b.x); fv[1] = bf2f(b.y); fv[2] = bf2f(b.z); fv[3] = bf2f(b.w);
            #pragma unroll
            for (int i = 0; i < 4; ++i)
                #pragma unroll
                for (int j = 0; j < 4; ++j) c[i][j] += wv[i] * fv[j];
            if (di == 0) {
                #pragma unroll
                for (int i = 0; i < 4; ++i) nrm[i] += wv[i];
            }
        }
        __syncthreads();
    }
    #pragma unroll
    for (int i = 0; i < 4; ++i)
        #pragma unroll
        for (int j = 0; j < 4; ++j)
            atomicAdd(&tok_raw[(h * 64 + gi * 4 + i) * 64 + di * 4 + j], c[i][j]);
    if (di == 0) {
        #pragma unroll
        for (int i = 0; i < 4; ++i) atomicAdd(&norm[h * 64 + gi * 4 + i], nrm[i]);
    }
}

// ---------------------------------------------------------------------------
// attn: per head, G=64 tokens: tokens = tok_raw/(norm+eps); q,k,v; softmax; Wo.
// 8 blocks x 64 threads (one thread per g).
// ---------------------------------------------------------------------------
__global__ __launch_bounds__(64)
void attn_kernel(const float* __restrict__ tok_raw, const float* __restrict__ norm,
                 const float* __restrict__ Wq, const float* __restrict__ Wk,
                 const float* __restrict__ Wv, const float* __restrict__ Wo,
                 float* __restrict__ out_tok) {
    int h = blockIdx.x;
    int g = threadIdx.x;
    __shared__ float tk[64][64], kk[64][64], vv[64][64];
    float inv = 1.f / (norm[h * 64 + g] + EPSF);
    for (int d = 0; d < 64; ++d) tk[g][d] = tok_raw[(size_t)(h * 64 + g) * 64 + d] * inv;
    __syncthreads();
    float q[64];
    #pragma unroll
    for (int o = 0; o < 64; ++o) {
        float sq = 0.f, sk = 0.f, sv = 0.f;
        #pragma unroll 8
        for (int d = 0; d < 64; ++d) {
            float t = tk[g][d];
            sq += t * Wq[o * 64 + d];
            sk += t * Wk[o * 64 + d];
            sv += t * Wv[o * 64 + d];
        }
        q[o] = sq; kk[g][o] = sk; vv[g][o] = sv;
    }
    __syncthreads();
    float s[64];
    float mx = -1e30f;
    #pragma unroll
    for (int j = 0; j < 64; ++j) {
        float a = 0.f;
        #pragma unroll 8
        for (int o = 0; o < 64; ++o) a += q[o] * kk[j][o];
        a *= 0.125f;                 // 1/sqrt(64)
        s[j] = a;
        mx = fmaxf(mx, a);
    }
    float sum = 0.f;
    #pragma unroll
    for (int j = 0; j < 64; ++j) { s[j] = __expf(s[j] - mx); sum += s[j]; }
    float isum = 1.f / sum;
    float od[64];
    #pragma unroll
    for (int d = 0; d < 64; ++d) od[d] = 0.f;
    for (int j = 0; j < 64; ++j) {
        float a = s[j] * isum;
        #pragma unroll
        for (int d = 0; d < 64; ++d) od[d] += a * vv[j][d];
    }
    #pragma unroll
    for (int o = 0; o < 64; ++o) {
        float v = 0.f;
        #pragma unroll 8
        for (int d = 0; d < 64; ++d) v += od[d] * Wo[o * 64 + d];
        out_tok[(size_t)(h * 64 + g) * 64 + o] = v;
    }
}

// ---------------------------------------------------------------------------
// fold2: V[o, h*64+g] = sum_d out_tok[h,g,d] * Wout[o, h*64+d]  (bf16 out)
// ---------------------------------------------------------------------------
__global__ void fold2_kernel(const float* __restrict__ out_tok,
                             const float* __restrict__ Wout, short* __restrict__ Vbf) {
    int idx = blockIdx.x * 256 + threadIdx.x;   // 0 .. 512*512-1
    int o = idx >> 9, hg = idx & 511;
    int h = hg >> 6;
    const float* ot = out_tok + (size_t)hg * 64;
    const float* wo = Wout + (size_t)o * 512 + h * 64;
    float s = 0.f;
    #pragma unroll 8
    for (int d = 0; d < 64; ++d) s += ot[d] * wo[d];
    Vbf[idx] = f2bf(s);
}

// ---------------------------------------------------------------------------
extern "C" void kernel_launch(void* const* d_in, const int* in_sizes, int n_in,
                              void* d_out, int out_size, void* d_ws, size_t ws_size,
                              hipStream_t stream) {
    const float* x    = (const float*)d_in[0];
    const float* Wx   = (const float*)d_in[1];
    const float* bx   = (const float*)d_in[2];
    const float* Wfx  = (const float*)d_in[3];
    const float* bfx  = (const float*)d_in[4];
    const float* Ws   = (const float*)d_in[5];
    const float* bs   = (const float*)d_in[6];
    const float* temp = (const float*)d_in[7];
    const float* Wq   = (const float*)d_in[8];
    const float* Wk   = (const float*)d_in[9];
    const float* Wv   = (const float*)d_in[10];
    const float* Wo   = (const float*)d_in[11];
    const float* Wout = (const float*)d_in[12];
    const float* bout = (const float*)d_in[13];

    const int N = in_sizes[0] / HID;

    // workspace carve-up (all 256B-aligned by construction)
    char* p = (char*)d_ws;
    short* mid = (short*)p;           p += (size_t)N * 1024 * 2;       // fx | logits->w (bf16)
    short* Wcat = (short*)p;          p += (size_t)1024 * 512 * 2;
    float* bias_cat = (float*)p;      p += 1024 * 4;
    float* tok_raw = (float*)p;       p += (size_t)NH * GG * DD * 4;   // contiguous with norm
    float* norm_ = (float*)p;         p += (size_t)NH * GG * 4;
    float* out_tok = (float*)p;       p += (size_t)NH * GG * DD * 4;
    short* Vbf = (short*)p;           p += (size_t)512 * 512 * 2;

    fold1_kernel<<<2048, 256, 0, stream>>>(Wx, bx, Wfx, bfx, Ws, bs, temp, Wcat, bias_cat);

    dim3 g1(8, (N + 127) / 128);
    gemm_bt<true, false><<<g1, 256, 0, stream>>>((const void*)x, HID, Wcat, bias_cat,
                                                 (void*)mid, 1024, N, 512);

    softmax_kernel<<<(N * 8 + 255) / 256, 256, 0, stream>>>(mid, N * 8);

    hipMemsetAsync(tok_raw, 0, (size_t)(NH * GG * DD + NH * GG) * 4, stream);

    int chunk = (N + 95) / 96;
    dim3 g2(96, 8);
    pool_kernel<<<g2, 256, 0, stream>>>(mid, tok_raw, norm_, N, chunk);

    attn_kernel<<<8, 64, 0, stream>>>(tok_raw, norm_, Wq, Wk, Wv, Wo, out_tok);

    fold2_kernel<<<1024, 256, 0, stream>>>(out_tok, Wout, Vbf);

    dim3 g3(4, (N + 127) / 128);
    gemm_bt<false, true><<<g3, 256, 0, stream>>>((const void*)(mid + 512), 1024, Vbf, bout,
                                                 d_out, HID, N, 512);
}

// Round 2
// 1275.261 us; speedup vs baseline: 1.0756x; 1.0756x over previous
//
#include <hip/hip_runtime.h>
#include <hip/hip_bf16.h>

#define HID 512
#define NH  8
#define DD  64
#define GG  64
#define EPSF 1e-5f

typedef __attribute__((ext_vector_type(8))) short short8;
typedef __attribute__((ext_vector_type(4))) short short4v;
typedef __attribute__((ext_vector_type(4))) float floatx4;

__device__ __forceinline__ short f2bf(float f) {
    union { float f; unsigned u; } v; v.f = f;
    unsigned r = v.u + 0x7fffu + ((v.u >> 16) & 1u);
    return (short)(r >> 16);
}
__device__ __forceinline__ float bf2f(short s) {
    union { unsigned u; float f; } v;
    v.u = ((unsigned)(unsigned short)s) << 16;
    return v.f;
}

// ---------------------------------------------------------------------------
// fold1: Wcat (1024x512 bf16) = [Wfx ; temp[h] * (Ws @ Wx_head)]
//        bias_cat (1024 f32)  = [bfx ; temp[h] * (Ws @ bx_head + bs)]
// ---------------------------------------------------------------------------
__global__ void fold1_kernel(const float* __restrict__ Wx, const float* __restrict__ bx,
                             const float* __restrict__ Wfx, const float* __restrict__ bfx,
                             const float* __restrict__ Ws, const float* __restrict__ bs,
                             const float* __restrict__ temp,
                             short* __restrict__ Wcat, float* __restrict__ bias_cat) {
    int idx = blockIdx.x * 256 + threadIdx.x;   // 0 .. 1024*512-1
    int row = idx >> 9;
    int k = idx & 511;
    float val;
    if (row < 512) {
        val = Wfx[row * 512 + k];
        if (k == 0) bias_cat[row] = bfx[row];
    } else {
        int hg = row - 512;
        int h = hg >> 6, g = hg & 63;
        float t = temp[h];
        float s = 0.f;
        #pragma unroll 8
        for (int d = 0; d < 64; ++d) s += Ws[g * 64 + d] * Wx[(h * 64 + d) * 512 + k];
        val = s * t;
        if (k == 0) {
            float b = 0.f;
            for (int d = 0; d < 64; ++d) b += Ws[g * 64 + d] * bx[h * 64 + d];
            bias_cat[row] = (b + bs[g]) * t;
        }
    }
    Wcat[idx] = f2bf(val);
}

// ---------------------------------------------------------------------------
// gemm_bt: C(M x ncols) = A(M x K) @ B(ncols x K)^T + bias, bf16 MFMA
//   A_F32: A is f32 (converted to bf16 in staging); else A is bf16 (short)
//   OUT_F32: C stored f32; else bf16 (short)
//   FUSE_SM: for col-blocks >= 512, apply 64-group softmax in the epilogue
// 128x128 block tile, 256 threads (4 waves in 2x2), 16x16x32 MFMA, 4x4/wave.
// 1-D grid with XCD-aware remap: id&7 -> XCD slice of row-tiles; the C
// col-blocks of one row-tile are consecutive ids on the SAME XCD so the A
// tile is L2-resident across them.  grid = 8 * ceil(R/8) * C
// ---------------------------------------------------------------------------
template <bool A_F32, bool OUT_F32, bool FUSE_SM>
__global__ __launch_bounds__(256, 4)
void gemm_bt(const void* __restrict__ Ap, int lda,
             const short* __restrict__ B,           // (ncols x K) bf16 row-major
             const float* __restrict__ bias,
             void* __restrict__ Cp, int ldc,
             int M, int K, int clog2, int Rtiles) {
    __shared__ short As[128 * 40];   // row stride 40 shorts (80 B): 2-way bank alias only
    __shared__ short Bs[128 * 40];

    const int id = blockIdx.x;
    const int xcd = id & 7;
    const int s = id >> 3;
    const int cblk = s & ((1 << clog2) - 1);
    const int slice = (Rtiles + 7) >> 3;
    const int rt = xcd * slice + (s >> clog2);
    if (rt >= Rtiles) return;

    const int tid = threadIdx.x;
    const int wid = tid >> 6, lane = tid & 63;
    const int col0 = cblk * 128;
    const int row0 = rt * 128;
    const int wm = (wid >> 1) * 64, wn = (wid & 1) * 64;
    const int lr = lane & 15, lq = lane >> 4;

    floatx4 acc[4][4];
    #pragma unroll
    for (int i = 0; i < 4; ++i)
        #pragma unroll
        for (int j = 0; j < 4; ++j) acc[i][j] = (floatx4)(0.f);

    for (int k0 = 0; k0 < K; k0 += 32) {
        if constexpr (A_F32) {
            const float* A = (const float*)Ap;
            #pragma unroll
            for (int it = 0; it < 4; ++it) {
                int c = tid + it * 256;          // 0..1023
                int r = c >> 3;                  // 0..127
                int kq = (c & 7) * 4;            // 0..28
                int gr = row0 + r;
                float4 v = make_float4(0.f, 0.f, 0.f, 0.f);
                if (gr < M) v = *(const float4*)(A + (size_t)gr * lda + k0 + kq);
                short4v hh;
                hh.x = f2bf(v.x); hh.y = f2bf(v.y); hh.z = f2bf(v.z); hh.w = f2bf(v.w);
                *(short4v*)&As[r * 40 + kq] = hh;
            }
        } else {
            const short* A = (const short*)Ap;
            #pragma unroll
            for (int it = 0; it < 2; ++it) {
                int c = tid + it * 256;          // 0..511
                int r = c >> 2;                  // 0..127
                int kq = (c & 3) * 8;            // 0,8,16,24
                int gr = row0 + r;
                short8 v = (short8)(0);
                if (gr < M) v = *(const short8*)(A + (size_t)gr * lda + k0 + kq);
                *(short8*)&As[r * 40 + kq] = v;
            }
        }
        #pragma unroll
        for (int it = 0; it < 2; ++it) {
            int c = tid + it * 256;
            int r = c >> 2;
            int kq = (c & 3) * 8;
            short8 v = *(const short8*)(B + (size_t)(col0 + r) * K + k0 + kq);
            *(short8*)&Bs[r * 40 + kq] = v;
        }
        __syncthreads();

        short8 af[4], bfr[4];
        #pragma unroll
        for (int i = 0; i < 4; ++i) af[i]  = *(const short8*)&As[(wm + i * 16 + lr) * 40 + lq * 8];
        #pragma unroll
        for (int j = 0; j < 4; ++j) bfr[j] = *(const short8*)&Bs[(wn + j * 16 + lr) * 40 + lq * 8];
        #pragma unroll
        for (int i = 0; i < 4; ++i)
            #pragma unroll
            for (int j = 0; j < 4; ++j)
                acc[i][j] = __builtin_amdgcn_mfma_f32_16x16x32_bf16(af[i], bfr[j], acc[i][j], 0, 0, 0);
        __syncthreads();
    }

    // epilogue: D[m][n]: col = lane&15, row = (lane>>4)*4 + reg  [measured m89/m91]
    // A wave's 64-col strip == one softmax group when col0>=512 (cols 64-aligned).
    const bool do_sm = FUSE_SM && (col0 >= 512);
    float bcol[4];
    #pragma unroll
    for (int j = 0; j < 4; ++j) bcol[j] = bias[col0 + wn + j * 16 + lr];

    #pragma unroll
    for (int i = 0; i < 4; ++i) {
        #pragma unroll
        for (int r = 0; r < 4; ++r) {
            int grow = row0 + wm + i * 16 + lq * 4 + r;
            float v[4];
            #pragma unroll
            for (int j = 0; j < 4; ++j) v[j] = acc[i][j][r] + bcol[j];
            if (do_sm) {
                float m = fmaxf(fmaxf(v[0], v[1]), fmaxf(v[2], v[3]));
                #pragma unroll
                for (int off = 1; off < 16; off <<= 1) m = fmaxf(m, __shfl_xor(m, off));
                float sum = 0.f;
                #pragma unroll
                for (int j = 0; j < 4; ++j) { v[j] = __expf(v[j] - m); sum += v[j]; }
                #pragma unroll
                for (int off = 1; off < 16; off <<= 1) sum += __shfl_xor(sum, off);
                float inv = 1.f / sum;
                #pragma unroll
                for (int j = 0; j < 4; ++j) v[j] *= inv;
            }
            if (grow < M) {
                #pragma unroll
                for (int j = 0; j < 4; ++j) {
                    int gcol = col0 + wn + j * 16 + lr;
                    if constexpr (OUT_F32) ((float*)Cp)[(size_t)grow * ldc + gcol] = v[j];
                    else                   ((short*)Cp)[(size_t)grow * ldc + gcol] = f2bf(v[j]);
                }
            }
        }
    }
}

// ---------------------------------------------------------------------------
// pooling: tok_raw[h,g,d] += sum_n w[n,h,g] * fx[n,h,d]; norm[h,g] += sum_n w
// grid (96, 8), 256 threads; thread owns a 4x4 (g,d) patch; atomics at end.
// ---------------------------------------------------------------------------
__global__ __launch_bounds__(256)
void pool_kernel(const short* __restrict__ mid, float* __restrict__ tok_raw,
                 float* __restrict__ norm, int N, int chunk) {
    int h = blockIdx.y;
    int n0 = blockIdx.x * chunk;
    int n1 = min(n0 + chunk, N);
    int tid = threadIdx.x;
    int gi = tid >> 4, di = tid & 15;
    __shared__ short ws_[16][64];
    __shared__ short fs_[16][64];
    float c[4][4] = {};
    float nrm[4] = {};
    for (int nb = n0; nb < n1; nb += 16) {
        int nrows = min(16, n1 - nb);
        {
            int r = tid >> 4;        // 0..15
            int seg = tid & 15;      // 0..15
            int n = nb + r;
            short8 v = (short8)(0);
            if (n < n1) {
                if (seg < 8) v = *(const short8*)(mid + (size_t)n * 1024 + 512 + h * 64 + seg * 8);
                else         v = *(const short8*)(mid + (size_t)n * 1024 + h * 64 + (seg - 8) * 8);
            }
            if (seg < 8) *(short8*)&ws_[r][seg * 8] = v;
            else         *(short8*)&fs_[r][(seg - 8) * 8] = v;
        }
        __syncthreads();
        for (int r = 0; r < nrows; ++r) {
            short4v a = *(const short4v*)&ws_[r][gi * 4];
            short4v b = *(const short4v*)&fs_[r][di * 4];
            float wv[4], fv[4];
            wv[0] = bf2f(a.x); wv[1] = bf2f(a.y); wv[2] = bf2f(a.z); wv[3] = bf2f(a.w);
            fv[0] = bf2f(b.x); fv[1] = bf2f(b.y); fv[2] = bf2f(b.z); fv[3] = bf2f(b.w);
            #pragma unroll
            for (int i = 0; i < 4; ++i)
                #pragma unroll
                for (int j = 0; j < 4; ++j) c[i][j] += wv[i] * fv[j];
            if (di == 0) {
                #pragma unroll
                for (int i = 0; i < 4; ++i) nrm[i] += wv[i];
            }
        }
        __syncthreads();
    }
    #pragma unroll
    for (int i = 0; i < 4; ++i)
        #pragma unroll
        for (int j = 0; j < 4; ++j)
            atomicAdd(&tok_raw[(h * 64 + gi * 4 + i) * 64 + di * 4 + j], c[i][j]);
    if (di == 0) {
        #pragma unroll
        for (int i = 0; i < 4; ++i) atomicAdd(&norm[h * 64 + gi * 4 + i], nrm[i]);
    }
}

// ---------------------------------------------------------------------------
// attn: per head, G=64 tokens: tokens = tok_raw/(norm+eps); q,k,v; softmax; Wo.
// 8 blocks x 64 threads (one thread per g).
// ---------------------------------------------------------------------------
__global__ __launch_bounds__(64)
void attn_kernel(const float* __restrict__ tok_raw, const float* __restrict__ norm,
                 const float* __restrict__ Wq, const float* __restrict__ Wk,
                 const float* __restrict__ Wv, const float* __restrict__ Wo,
                 float* __restrict__ out_tok) {
    int h = blockIdx.x;
    int g = threadIdx.x;
    __shared__ float tk[64][64], kk[64][64], vv[64][64];
    float inv = 1.f / (norm[h * 64 + g] + EPSF);
    for (int d = 0; d < 64; ++d) tk[g][d] = tok_raw[(size_t)(h * 64 + g) * 64 + d] * inv;
    __syncthreads();
    float q[64];
    #pragma unroll
    for (int o = 0; o < 64; ++o) {
        float sq = 0.f, sk = 0.f, sv = 0.f;
        #pragma unroll 8
        for (int d = 0; d < 64; ++d) {
            float t = tk[g][d];
            sq += t * Wq[o * 64 + d];
            sk += t * Wk[o * 64 + d];
            sv += t * Wv[o * 64 + d];
        }
        q[o] = sq; kk[g][o] = sk; vv[g][o] = sv;
    }
    __syncthreads();
    float s[64];
    float mx = -1e30f;
    #pragma unroll
    for (int j = 0; j < 64; ++j) {
        float a = 0.f;
        #pragma unroll 8
        for (int o = 0; o < 64; ++o) a += q[o] * kk[j][o];
        a *= 0.125f;                 // 1/sqrt(64)
        s[j] = a;
        mx = fmaxf(mx, a);
    }
    float sum = 0.f;
    #pragma unroll
    for (int j = 0; j < 64; ++j) { s[j] = __expf(s[j] - mx); sum += s[j]; }
    float isum = 1.f / sum;
    float od[64];
    #pragma unroll
    for (int d = 0; d < 64; ++d) od[d] = 0.f;
    for (int j = 0; j < 64; ++j) {
        float a = s[j] * isum;
        #pragma unroll
        for (int d = 0; d < 64; ++d) od[d] += a * vv[j][d];
    }
    #pragma unroll
    for (int o = 0; o < 64; ++o) {
        float v = 0.f;
        #pragma unroll 8
        for (int d = 0; d < 64; ++d) v += od[d] * Wo[o * 64 + d];
        out_tok[(size_t)(h * 64 + g) * 64 + o] = v;
    }
}

// ---------------------------------------------------------------------------
// fold2: V[o, h*64+g] = sum_d out_tok[h,g,d] * Wout[o, h*64+d]  (bf16 out)
// ---------------------------------------------------------------------------
__global__ void fold2_kernel(const float* __restrict__ out_tok,
                             const float* __restrict__ Wout, short* __restrict__ Vbf) {
    int idx = blockIdx.x * 256 + threadIdx.x;   // 0 .. 512*512-1
    int o = idx >> 9, hg = idx & 511;
    int h = hg >> 6;
    const float* ot = out_tok + (size_t)hg * 64;
    const float* wo = Wout + (size_t)o * 512 + h * 64;
    float s = 0.f;
    #pragma unroll 8
    for (int d = 0; d < 64; ++d) s += ot[d] * wo[d];
    Vbf[idx] = f2bf(s);
}

// ---------------------------------------------------------------------------
extern "C" void kernel_launch(void* const* d_in, const int* in_sizes, int n_in,
                              void* d_out, int out_size, void* d_ws, size_t ws_size,
                              hipStream_t stream) {
    const float* x    = (const float*)d_in[0];
    const float* Wx   = (const float*)d_in[1];
    const float* bx   = (const float*)d_in[2];
    const float* Wfx  = (const float*)d_in[3];
    const float* bfx  = (const float*)d_in[4];
    const float* Ws   = (const float*)d_in[5];
    const float* bs   = (const float*)d_in[6];
    const float* temp = (const float*)d_in[7];
    const float* Wq   = (const float*)d_in[8];
    const float* Wk   = (const float*)d_in[9];
    const float* Wv   = (const float*)d_in[10];
    const float* Wo   = (const float*)d_in[11];
    const float* Wout = (const float*)d_in[12];
    const float* bout = (const float*)d_in[13];

    const int N = in_sizes[0] / HID;

    // workspace carve-up
    char* p = (char*)d_ws;
    short* mid = (short*)p;           p += (size_t)N * 1024 * 2;       // fx | w (bf16)
    short* Wcat = (short*)p;          p += (size_t)1024 * 512 * 2;
    float* bias_cat = (float*)p;      p += 1024 * 4;
    float* tok_raw = (float*)p;       p += (size_t)NH * GG * DD * 4;   // contiguous with norm
    float* norm_ = (float*)p;         p += (size_t)NH * GG * 4;
    float* out_tok = (float*)p;       p += (size_t)NH * GG * DD * 4;
    short* Vbf = (short*)p;           p += (size_t)512 * 512 * 2;

    fold1_kernel<<<2048, 256, 0, stream>>>(Wx, bx, Wfx, bfx, Ws, bs, temp, Wcat, bias_cat);

    const int R = (N + 127) / 128;          // 782 row tiles
    const int slice = (R + 7) / 8;          // 98

    // GEMM1: C=8 col tiles, fused softmax on logits half
    gemm_bt<true, false, true><<<8 * slice * 8, 256, 0, stream>>>(
        (const void*)x, HID, Wcat, bias_cat, (void*)mid, 1024, N, 512, 3, R);

    hipMemsetAsync(tok_raw, 0, (size_t)(NH * GG * DD + NH * GG) * 4, stream);

    int chunk = (N + 95) / 96;
    dim3 g2(96, 8);
    pool_kernel<<<g2, 256, 0, stream>>>(mid, tok_raw, norm_, N, chunk);

    attn_kernel<<<8, 64, 0, stream>>>(tok_raw, norm_, Wq, Wk, Wv, Wo, out_tok);

    fold2_kernel<<<1024, 256, 0, stream>>>(out_tok, Wout, Vbf);

    // GEMM2: C=4 col tiles
    gemm_bt<false, true, false><<<8 * slice * 4, 256, 0, stream>>>(
        (const void*)(mid + 512), 1024, Vbf, bout, d_out, HID, N, 512, 2, R);
}

// Round 3
// 1142.171 us; speedup vs baseline: 1.2010x; 1.1165x over previous
//
#include <hip/hip_runtime.h>
#include <hip/hip_bf16.h>

#define HID 512
#define NH  8
#define DD  64
#define GG  64
#define EPSF 1e-5f

typedef __attribute__((ext_vector_type(8))) short short8;
typedef __attribute__((ext_vector_type(4))) short short4v;
typedef __attribute__((ext_vector_type(4))) float floatx4;

__device__ __forceinline__ short f2bf(float f) {
    union { float f; unsigned u; } v; v.f = f;
    unsigned r = v.u + 0x7fffu + ((v.u >> 16) & 1u);
    return (short)(r >> 16);
}
__device__ __forceinline__ float bf2f(short s) {
    union { unsigned u; float f; } v;
    v.u = ((unsigned)(unsigned short)s) << 16;
    return v.f;
}

#define GLOAD_LDS16(g, l) __builtin_amdgcn_global_load_lds( \
    (const __attribute__((address_space(1))) unsigned int*)(g), \
    (__attribute__((address_space(3))) unsigned int*)(l), 16, 0, 0)

// ---------------------------------------------------------------------------
// cast x (f32) -> x_bf (bf16), 8 elems/thread
// ---------------------------------------------------------------------------
__global__ __launch_bounds__(256)
void cast_kernel(const float* __restrict__ x, short* __restrict__ xb, int n8) {
    int i = blockIdx.x * 256 + threadIdx.x;
    if (i >= n8) return;
    const float4* p = (const float4*)(x + (size_t)i * 8);
    float4 a = p[0], b = p[1];
    short8 v;
    v[0] = f2bf(a.x); v[1] = f2bf(a.y); v[2] = f2bf(a.z); v[3] = f2bf(a.w);
    v[4] = f2bf(b.x); v[5] = f2bf(b.y); v[6] = f2bf(b.z); v[7] = f2bf(b.w);
    *(short8*)(xb + (size_t)i * 8) = v;
}

// ---------------------------------------------------------------------------
// fold1: Wcat (1024x512 bf16) = [Wfx ; temp[h] * (Ws @ Wx_head)]
//        bias_cat (1024 f32)  = [bfx ; temp[h] * (Ws @ bx_head + bs)]
// ---------------------------------------------------------------------------
__global__ void fold1_kernel(const float* __restrict__ Wx, const float* __restrict__ bx,
                             const float* __restrict__ Wfx, const float* __restrict__ bfx,
                             const float* __restrict__ Ws, const float* __restrict__ bs,
                             const float* __restrict__ temp,
                             short* __restrict__ Wcat, float* __restrict__ bias_cat) {
    int idx = blockIdx.x * 256 + threadIdx.x;   // 0 .. 1024*512-1
    int row = idx >> 9;
    int k = idx & 511;
    float val;
    if (row < 512) {
        val = Wfx[row * 512 + k];
        if (k == 0) bias_cat[row] = bfx[row];
    } else {
        int hg = row - 512;
        int h = hg >> 6, g = hg & 63;
        float t = temp[h];
        float s = 0.f;
        #pragma unroll 8
        for (int d = 0; d < 64; ++d) s += Ws[g * 64 + d] * Wx[(h * 64 + d) * 512 + k];
        val = s * t;
        if (k == 0) {
            float b = 0.f;
            for (int d = 0; d < 64; ++d) b += Ws[g * 64 + d] * bx[h * 64 + d];
            bias_cat[row] = (b + bs[g]) * t;
        }
    }
    Wcat[idx] = f2bf(val);
}

// ---------------------------------------------------------------------------
// gemm_bt: C(M x ncols) = A(M x K) @ B(ncols x K)^T + bias, bf16 MFMA
// m97 structure: global_load_lds width=16 staging, unpadded LDS stride 32
// shorts with XOR swizzle (chunk kc of row r at slot kc ^ ((r>>1)&3)) to
// break bank conflicts. 128x128 tile, 4 waves 2x2, 16x16x32 MFMA, 4x4/wave.
// 1-D grid, XCD-aware remap (id&7 = XCD): the C col-blocks of one row-tile
// are consecutive on one XCD -> A tile L2-resident.  grid = 8*ceil(R/8)*C
// NOTE: A rows >= M are loaded unguarded (reads stay inside the enclosing
// buffer; results masked at store) — callers guarantee buffer slack.
// ---------------------------------------------------------------------------
template <bool OUT_F32, bool FUSE_SM>
__global__ __launch_bounds__(256, 4)
void gemm_bt(const short* __restrict__ A, int lda,
             const short* __restrict__ B,           // (ncols x K) bf16 row-major
             const float* __restrict__ bias,
             void* __restrict__ Cp, int ldc,
             int M, int K, int clog2, int Rtiles) {
    __shared__ short As[128 * 32];   // unpadded: row = 32 shorts = 4 chunks of 16B
    __shared__ short Bs[128 * 32];

    const int id = blockIdx.x;
    const int xcd = id & 7;
    const int s = id >> 3;
    const int cblk = s & ((1 << clog2) - 1);
    const int slice = (Rtiles + 7) >> 3;
    const int rt = xcd * slice + (s >> clog2);
    if (rt >= Rtiles) return;

    const int tid = threadIdx.x;
    const int wid = tid >> 6, lane = tid & 63;
    const int col0 = cblk * 128;
    const int row0 = rt * 128;
    const int wm = (wid >> 1) * 64, wn = (wid & 1) * 64;
    const int lr = lane & 15, lq = lane >> 4;

    // staging: chunk c = tid + it*256 (c = row*4 + slot); LDS addr = c*16 B.
    // global source chunk kc = slot ^ ((row>>1)&3).
    int st_row[2], st_kc[2];
    #pragma unroll
    for (int it = 0; it < 2; ++it) {
        int c = tid + it * 256;
        st_row[it] = c >> 2;
        st_kc[it] = (c & 3) ^ ((st_row[it] >> 1) & 3);
    }
    // fragment read xor (loop-invariant): slot = lq ^ ((lr>>1)&3)
    const int fx_ = lq ^ ((lr >> 1) & 3);

    floatx4 acc[4][4];
    #pragma unroll
    for (int i = 0; i < 4; ++i)
        #pragma unroll
        for (int j = 0; j < 4; ++j) acc[i][j] = (floatx4)(0.f);

    const short* Abase = A + (size_t)row0 * lda;
    const short* Bbase = B + (size_t)col0 * lda;   // lda == K for B too

    for (int k0 = 0; k0 < K; k0 += 32) {
        #pragma unroll
        for (int it = 0; it < 2; ++it) {
            // wave-uniform LDS base: chunks [wid*64 + it*256 .. +64) ; lane i -> +i*16
            short* ldsA = As + (wid * 64 + it * 256) * 8;
            short* ldsB = Bs + (wid * 64 + it * 256) * 8;
            GLOAD_LDS16(Abase + (size_t)st_row[it] * lda + k0 + st_kc[it] * 8, ldsA);
            GLOAD_LDS16(Bbase + (size_t)st_row[it] * lda + k0 + st_kc[it] * 8, ldsB);
        }
        __syncthreads();

        short8 af[4], bfr[4];
        #pragma unroll
        for (int i = 0; i < 4; ++i) af[i]  = *(const short8*)&As[(wm + i * 16 + lr) * 32 + fx_ * 8];
        #pragma unroll
        for (int j = 0; j < 4; ++j) bfr[j] = *(const short8*)&Bs[(wn + j * 16 + lr) * 32 + fx_ * 8];
        #pragma unroll
        for (int i = 0; i < 4; ++i)
            #pragma unroll
            for (int j = 0; j < 4; ++j)
                acc[i][j] = __builtin_amdgcn_mfma_f32_16x16x32_bf16(af[i], bfr[j], acc[i][j], 0, 0, 0);
        __syncthreads();
    }

    // epilogue: D[m][n]: col = lane&15, row = (lane>>4)*4 + reg  [m89/m91]
    const bool do_sm = FUSE_SM && (col0 >= 512);
    float bcol[4];
    #pragma unroll
    for (int j = 0; j < 4; ++j) bcol[j] = bias[col0 + wn + j * 16 + lr];

    #pragma unroll
    for (int i = 0; i < 4; ++i) {
        #pragma unroll
        for (int r = 0; r < 4; ++r) {
            int grow = row0 + wm + i * 16 + lq * 4 + r;
            float v[4];
            #pragma unroll
            for (int j = 0; j < 4; ++j) v[j] = acc[i][j][r] + bcol[j];
            if (do_sm) {
                float m = fmaxf(fmaxf(v[0], v[1]), fmaxf(v[2], v[3]));
                #pragma unroll
                for (int off = 1; off < 16; off <<= 1) m = fmaxf(m, __shfl_xor(m, off));
                float sum = 0.f;
                #pragma unroll
                for (int j = 0; j < 4; ++j) { v[j] = __expf(v[j] - m); sum += v[j]; }
                #pragma unroll
                for (int off = 1; off < 16; off <<= 1) sum += __shfl_xor(sum, off);
                float inv = 1.f / sum;
                #pragma unroll
                for (int j = 0; j < 4; ++j) v[j] *= inv;
            }
            if (grow < M) {
                #pragma unroll
                for (int j = 0; j < 4; ++j) {
                    int gcol = col0 + wn + j * 16 + lr;
                    if constexpr (OUT_F32) ((float*)Cp)[(size_t)grow * ldc + gcol] = v[j];
                    else                   ((short*)Cp)[(size_t)grow * ldc + gcol] = f2bf(v[j]);
                }
            }
        }
    }
}

// ---------------------------------------------------------------------------
// pooling: tok_raw[h,g,d] += sum_n w[n,h,g] * fx[n,h,d]; norm[h,g] += sum_n w
// ---------------------------------------------------------------------------
__global__ __launch_bounds__(256)
void pool_kernel(const short* __restrict__ mid, float* __restrict__ tok_raw,
                 float* __restrict__ norm, int N, int chunk) {
    int h = blockIdx.y;
    int n0 = blockIdx.x * chunk;
    int n1 = min(n0 + chunk, N);
    int tid = threadIdx.x;
    int gi = tid >> 4, di = tid & 15;
    __shared__ short ws_[16][64];
    __shared__ short fs_[16][64];
    float c[4][4] = {};
    float nrm[4] = {};
    for (int nb = n0; nb < n1; nb += 16) {
        int nrows = min(16, n1 - nb);
        {
            int r = tid >> 4;
            int seg = tid & 15;
            int n = nb + r;
            short8 v = (short8)(0);
            if (n < n1) {
                if (seg < 8) v = *(const short8*)(mid + (size_t)n * 1024 + 512 + h * 64 + seg * 8);
                else         v = *(const short8*)(mid + (size_t)n * 1024 + h * 64 + (seg - 8) * 8);
            }
            if (seg < 8) *(short8*)&ws_[r][seg * 8] = v;
            else         *(short8*)&fs_[r][(seg - 8) * 8] = v;
        }
        __syncthreads();
        for (int r = 0; r < nrows; ++r) {
            short4v a = *(const short4v*)&ws_[r][gi * 4];
            short4v b = *(const short4v*)&fs_[r][di * 4];
            float wv[4], fv[4];
            wv[0] = bf2f(a.x); wv[1] = bf2f(a.y); wv[2] = bf2f(a.z); wv[3] = bf2f(a.w);
            fv[0] = bf2f(b.x); fv[1] = bf2f(b.y); fv[2] = bf2f(b.z); fv[3] = bf2f(b.w);
            #pragma unroll
            for (int i = 0; i < 4; ++i)
                #pragma unroll
                for (int j = 0; j < 4; ++j) c[i][j] += wv[i] * fv[j];
            if (di == 0) {
                #pragma unroll
                for (int i = 0; i < 4; ++i) nrm[i] += wv[i];
            }
        }
        __syncthreads();
    }
    #pragma unroll
    for (int i = 0; i < 4; ++i)
        #pragma unroll
        for (int j = 0; j < 4; ++j)
            atomicAdd(&tok_raw[(h * 64 + gi * 4 + i) * 64 + di * 4 + j], c[i][j]);
    if (di == 0) {
        #pragma unroll
        for (int i = 0; i < 4; ++i) atomicAdd(&norm[h * 64 + gi * 4 + i], nrm[i]);
    }
}

// ---------------------------------------------------------------------------
// attn: per head, G=64 tokens: tokens = tok_raw/(norm+eps); q,k,v; softmax; Wo.
// ---------------------------------------------------------------------------
__global__ __launch_bounds__(64)
void attn_kernel(const float* __restrict__ tok_raw, const float* __restrict__ norm,
                 const float* __restrict__ Wq, const float* __restrict__ Wk,
                 const float* __restrict__ Wv, const float* __restrict__ Wo,
                 float* __restrict__ out_tok) {
    int h = blockIdx.x;
    int g = threadIdx.x;
    __shared__ float tk[64][64], kk[64][64], vv[64][64];
    float inv = 1.f / (norm[h * 64 + g] + EPSF);
    for (int d = 0; d < 64; ++d) tk[g][d] = tok_raw[(size_t)(h * 64 + g) * 64 + d] * inv;
    __syncthreads();
    float q[64];
    #pragma unroll
    for (int o = 0; o < 64; ++o) {
        float sq = 0.f, sk = 0.f, sv = 0.f;
        #pragma unroll 8
        for (int d = 0; d < 64; ++d) {
            float t = tk[g][d];
            sq += t * Wq[o * 64 + d];
            sk += t * Wk[o * 64 + d];
            sv += t * Wv[o * 64 + d];
        }
        q[o] = sq; kk[g][o] = sk; vv[g][o] = sv;
    }
    __syncthreads();
    float s[64];
    float mx = -1e30f;
    #pragma unroll
    for (int j = 0; j < 64; ++j) {
        float a = 0.f;
        #pragma unroll 8
        for (int o = 0; o < 64; ++o) a += q[o] * kk[j][o];
        a *= 0.125f;
        s[j] = a;
        mx = fmaxf(mx, a);
    }
    float sum = 0.f;
    #pragma unroll
    for (int j = 0; j < 64; ++j) { s[j] = __expf(s[j] - mx); sum += s[j]; }
    float isum = 1.f / sum;
    float od[64];
    #pragma unroll
    for (int d = 0; d < 64; ++d) od[d] = 0.f;
    for (int j = 0; j < 64; ++j) {
        float a = s[j] * isum;
        #pragma unroll
        for (int d = 0; d < 64; ++d) od[d] += a * vv[j][d];
    }
    #pragma unroll
    for (int o = 0; o < 64; ++o) {
        float v = 0.f;
        #pragma unroll 8
        for (int d = 0; d < 64; ++d) v += od[d] * Wo[o * 64 + d];
        out_tok[(size_t)(h * 64 + g) * 64 + o] = v;
    }
}

// ---------------------------------------------------------------------------
// fold2: V[o, h*64+g] = sum_d out_tok[h,g,d] * Wout[o, h*64+d]  (bf16 out)
// ---------------------------------------------------------------------------
__global__ void fold2_kernel(const float* __restrict__ out_tok,
                             const float* __restrict__ Wout, short* __restrict__ Vbf) {
    int idx = blockIdx.x * 256 + threadIdx.x;
    int o = idx >> 9, hg = idx & 511;
    int h = hg >> 6;
    const float* ot = out_tok + (size_t)hg * 64;
    const float* wo = Wout + (size_t)o * 512 + h * 64;
    float s = 0.f;
    #pragma unroll 8
    for (int d = 0; d < 64; ++d) s += ot[d] * wo[d];
    Vbf[idx] = f2bf(s);
}

// ---------------------------------------------------------------------------
extern "C" void kernel_launch(void* const* d_in, const int* in_sizes, int n_in,
                              void* d_out, int out_size, void* d_ws, size_t ws_size,
                              hipStream_t stream) {
    const float* x    = (const float*)d_in[0];
    const float* Wx   = (const float*)d_in[1];
    const float* bx   = (const float*)d_in[2];
    const float* Wfx  = (const float*)d_in[3];
    const float* bfx  = (const float*)d_in[4];
    const float* Ws   = (const float*)d_in[5];
    const float* bs   = (const float*)d_in[6];
    const float* temp = (const float*)d_in[7];
    const float* Wq   = (const float*)d_in[8];
    const float* Wk   = (const float*)d_in[9];
    const float* Wv   = (const float*)d_in[10];
    const float* Wo   = (const float*)d_in[11];
    const float* Wout = (const float*)d_in[12];
    const float* bout = (const float*)d_in[13];

    const int N = in_sizes[0] / HID;

    // workspace carve-up (x_bf lives in d_out until GEMM2 overwrites it:
    // d_out is N*512 f32 = 2x the bytes of x_bf, and GEMM2 doesn't read d_out)
    char* p = (char*)d_ws;
    short* mid = (short*)p;           p += (size_t)N * 1024 * 2;       // fx | w (bf16)
    short* Wcat = (short*)p;          p += (size_t)1024 * 512 * 2;
    float* bias_cat = (float*)p;      p += 1024 * 4;
    float* tok_raw = (float*)p;       p += (size_t)NH * GG * DD * 4;   // contiguous with norm
    float* norm_ = (float*)p;         p += (size_t)NH * GG * 4;
    float* out_tok = (float*)p;       p += (size_t)NH * GG * DD * 4;
    short* Vbf = (short*)p;           p += (size_t)512 * 512 * 2;
    short* x_bf = (short*)d_out;

    cast_kernel<<<(N * 512 / 8 + 255) / 256, 256, 0, stream>>>(x, x_bf, N * 512 / 8);
    fold1_kernel<<<2048, 256, 0, stream>>>(Wx, bx, Wfx, bfx, Ws, bs, temp, Wcat, bias_cat);

    const int R = (N + 127) / 128;          // row tiles
    const int slice = (R + 7) / 8;

    // GEMM1: C=8 col tiles, fused softmax on logits half
    gemm_bt<false, true><<<8 * slice * 8, 256, 0, stream>>>(
        x_bf, HID, Wcat, bias_cat, (void*)mid, 1024, N, 512, 3, R);

    hipMemsetAsync(tok_raw, 0, (size_t)(NH * GG * DD + NH * GG) * 4, stream);

    int chunk = (N + 95) / 96;
    dim3 g2(96, 8);
    pool_kernel<<<g2, 256, 0, stream>>>(mid, tok_raw, norm_, N, chunk);

    attn_kernel<<<8, 64, 0, stream>>>(tok_raw, norm_, Wq, Wk, Wv, Wo, out_tok);

    fold2_kernel<<<1024, 256, 0, stream>>>(out_tok, Wout, Vbf);

    // GEMM2: C=4 col tiles (A = w half of mid, bf16; output f32 + bout)
    gemm_bt<true, false><<<8 * slice * 4, 256, 0, stream>>>(
        mid + 512, 1024, Vbf, bout, d_out, HID, N, 512, 2, R);
}

// Round 4
// 886.021 us; speedup vs baseline: 1.5482x; 1.2891x over previous
//
#include <hip/hip_runtime.h>
#include <hip/hip_bf16.h>

#define HID 512
#define NH  8
#define DD  64
#define GG  64
#define EPSF 1e-5f

typedef __attribute__((ext_vector_type(8))) short short8;
typedef __attribute__((ext_vector_type(4))) short short4v;
typedef __attribute__((ext_vector_type(4))) float floatx4;

__device__ __forceinline__ short f2bf(float f) {
    union { float f; unsigned u; } v; v.f = f;
    unsigned r = v.u + 0x7fffu + ((v.u >> 16) & 1u);
    return (short)(r >> 16);
}
__device__ __forceinline__ float bf2f(short s) {
    union { unsigned u; float f; } v;
    v.u = ((unsigned)(unsigned short)s) << 16;
    return v.f;
}

#define GLOAD_LDS16(g, l) __builtin_amdgcn_global_load_lds( \
    (const __attribute__((address_space(1))) unsigned int*)(g), \
    (__attribute__((address_space(3))) unsigned int*)(l), 16, 0, 0)

// ---------------------------------------------------------------------------
// cast x (f32) -> x_bf (bf16), 8 elems/thread
// ---------------------------------------------------------------------------
__global__ __launch_bounds__(256)
void cast_kernel(const float* __restrict__ x, short* __restrict__ xb, int n8) {
    int i = blockIdx.x * 256 + threadIdx.x;
    if (i >= n8) return;
    const float4* p = (const float4*)(x + (size_t)i * 8);
    float4 a = p[0], b = p[1];
    short8 v;
    v[0] = f2bf(a.x); v[1] = f2bf(a.y); v[2] = f2bf(a.z); v[3] = f2bf(a.w);
    v[4] = f2bf(b.x); v[5] = f2bf(b.y); v[6] = f2bf(b.z); v[7] = f2bf(b.w);
    *(short8*)(xb + (size_t)i * 8) = v;
}

// ---------------------------------------------------------------------------
// fold1: Wcat (1024x512 bf16) = [Wfx ; temp[h] * (Ws @ Wx_head)]
//        bias_cat (1024 f32)  = [bfx ; temp[h] * (Ws @ bx_head + bs)]
// ---------------------------------------------------------------------------
__global__ void fold1_kernel(const float* __restrict__ Wx, const float* __restrict__ bx,
                             const float* __restrict__ Wfx, const float* __restrict__ bfx,
                             const float* __restrict__ Ws, const float* __restrict__ bs,
                             const float* __restrict__ temp,
                             short* __restrict__ Wcat, float* __restrict__ bias_cat) {
    int idx = blockIdx.x * 256 + threadIdx.x;   // 0 .. 1024*512-1
    int row = idx >> 9;
    int k = idx & 511;
    float val;
    if (row < 512) {
        val = Wfx[row * 512 + k];
        if (k == 0) bias_cat[row] = bfx[row];
    } else {
        int hg = row - 512;
        int h = hg >> 6, g = hg & 63;
        float t = temp[h];
        float s = 0.f;
        #pragma unroll 8
        for (int d = 0; d < 64; ++d) s += Ws[g * 64 + d] * Wx[(h * 64 + d) * 512 + k];
        val = s * t;
        if (k == 0) {
            float b = 0.f;
            for (int d = 0; d < 64; ++d) b += Ws[g * 64 + d] * bx[h * 64 + d];
            bias_cat[row] = (b + bs[g]) * t;
        }
    }
    Wcat[idx] = f2bf(val);
}

// ---------------------------------------------------------------------------
// gemm_bt: C(M x ncols) = A(M x K) @ B(ncols x K)^T + bias, bf16 MFMA
// m97 structure: global_load_lds width=16 staging, unpadded LDS stride 32
// shorts with XOR swizzle (chunk kc of row r at slot kc ^ ((r>>1)&3)).
// 128x128 tile, 4 waves 2x2, 16x16x32 MFMA, 4x4/wave. XCD-aware 1-D grid.
// ---------------------------------------------------------------------------
template <bool OUT_F32, bool FUSE_SM>
__global__ __launch_bounds__(256, 4)
void gemm_bt(const short* __restrict__ A, int lda,
             const short* __restrict__ B,           // (ncols x K) bf16 row-major
             const float* __restrict__ bias,
             void* __restrict__ Cp, int ldc,
             int M, int K, int clog2, int Rtiles) {
    __shared__ short As[128 * 32];
    __shared__ short Bs[128 * 32];

    const int id = blockIdx.x;
    const int xcd = id & 7;
    const int s = id >> 3;
    const int cblk = s & ((1 << clog2) - 1);
    const int slice = (Rtiles + 7) >> 3;
    const int rt = xcd * slice + (s >> clog2);
    if (rt >= Rtiles) return;

    const int tid = threadIdx.x;
    const int wid = tid >> 6, lane = tid & 63;
    const int col0 = cblk * 128;
    const int row0 = rt * 128;
    const int wm = (wid >> 1) * 64, wn = (wid & 1) * 64;
    const int lr = lane & 15, lq = lane >> 4;

    int st_row[2], st_kc[2];
    #pragma unroll
    for (int it = 0; it < 2; ++it) {
        int c = tid + it * 256;
        st_row[it] = c >> 2;
        st_kc[it] = (c & 3) ^ ((st_row[it] >> 1) & 3);
    }
    const int fx_ = lq ^ ((lr >> 1) & 3);

    floatx4 acc[4][4];
    #pragma unroll
    for (int i = 0; i < 4; ++i)
        #pragma unroll
        for (int j = 0; j < 4; ++j) acc[i][j] = (floatx4)(0.f);

    const short* Abase = A + (size_t)row0 * lda;
    const short* Bbase = B + (size_t)col0 * lda;

    for (int k0 = 0; k0 < K; k0 += 32) {
        #pragma unroll
        for (int it = 0; it < 2; ++it) {
            short* ldsA = As + (wid * 64 + it * 256) * 8;
            short* ldsB = Bs + (wid * 64 + it * 256) * 8;
            GLOAD_LDS16(Abase + (size_t)st_row[it] * lda + k0 + st_kc[it] * 8, ldsA);
            GLOAD_LDS16(Bbase + (size_t)st_row[it] * lda + k0 + st_kc[it] * 8, ldsB);
        }
        __syncthreads();

        short8 af[4], bfr[4];
        #pragma unroll
        for (int i = 0; i < 4; ++i) af[i]  = *(const short8*)&As[(wm + i * 16 + lr) * 32 + fx_ * 8];
        #pragma unroll
        for (int j = 0; j < 4; ++j) bfr[j] = *(const short8*)&Bs[(wn + j * 16 + lr) * 32 + fx_ * 8];
        #pragma unroll
        for (int i = 0; i < 4; ++i)
            #pragma unroll
            for (int j = 0; j < 4; ++j)
                acc[i][j] = __builtin_amdgcn_mfma_f32_16x16x32_bf16(af[i], bfr[j], acc[i][j], 0, 0, 0);
        __syncthreads();
    }

    const bool do_sm = FUSE_SM && (col0 >= 512);
    float bcol[4];
    #pragma unroll
    for (int j = 0; j < 4; ++j) bcol[j] = bias[col0 + wn + j * 16 + lr];

    #pragma unroll
    for (int i = 0; i < 4; ++i) {
        #pragma unroll
        for (int r = 0; r < 4; ++r) {
            int grow = row0 + wm + i * 16 + lq * 4 + r;
            float v[4];
            #pragma unroll
            for (int j = 0; j < 4; ++j) v[j] = acc[i][j][r] + bcol[j];
            if (do_sm) {
                float m = fmaxf(fmaxf(v[0], v[1]), fmaxf(v[2], v[3]));
                #pragma unroll
                for (int off = 1; off < 16; off <<= 1) m = fmaxf(m, __shfl_xor(m, off));
                float sum = 0.f;
                #pragma unroll
                for (int j = 0; j < 4; ++j) { v[j] = __expf(v[j] - m); sum += v[j]; }
                #pragma unroll
                for (int off = 1; off < 16; off <<= 1) sum += __shfl_xor(sum, off);
                float inv = 1.f / sum;
                #pragma unroll
                for (int j = 0; j < 4; ++j) v[j] *= inv;
            }
            if (grow < M) {
                #pragma unroll
                for (int j = 0; j < 4; ++j) {
                    int gcol = col0 + wn + j * 16 + lr;
                    if constexpr (OUT_F32) ((float*)Cp)[(size_t)grow * ldc + gcol] = v[j];
                    else                   ((short*)Cp)[(size_t)grow * ldc + gcol] = f2bf(v[j]);
                }
            }
        }
    }
}

// ---------------------------------------------------------------------------
// pooling: tok_raw[h,g,d] += sum_n w[n,h,g] * fx[n,h,d]; norm[h,g] += sum_n w
// ---------------------------------------------------------------------------
__global__ __launch_bounds__(256)
void pool_kernel(const short* __restrict__ mid, float* __restrict__ tok_raw,
                 float* __restrict__ norm, int N, int chunk) {
    int h = blockIdx.y;
    int n0 = blockIdx.x * chunk;
    int n1 = min(n0 + chunk, N);
    int tid = threadIdx.x;
    int gi = tid >> 4, di = tid & 15;
    __shared__ short ws_[16][64];
    __shared__ short fs_[16][64];
    float c[4][4] = {};
    float nrm[4] = {};
    for (int nb = n0; nb < n1; nb += 16) {
        int nrows = min(16, n1 - nb);
        {
            int r = tid >> 4;
            int seg = tid & 15;
            int n = nb + r;
            short8 v = (short8)(0);
            if (n < n1) {
                if (seg < 8) v = *(const short8*)(mid + (size_t)n * 1024 + 512 + h * 64 + seg * 8);
                else         v = *(const short8*)(mid + (size_t)n * 1024 + h * 64 + (seg - 8) * 8);
            }
            if (seg < 8) *(short8*)&ws_[r][seg * 8] = v;
            else         *(short8*)&fs_[r][(seg - 8) * 8] = v;
        }
        __syncthreads();
        for (int r = 0; r < nrows; ++r) {
            short4v a = *(const short4v*)&ws_[r][gi * 4];
            short4v b = *(const short4v*)&fs_[r][di * 4];
            float wv[4], fv[4];
            wv[0] = bf2f(a.x); wv[1] = bf2f(a.y); wv[2] = bf2f(a.z); wv[3] = bf2f(a.w);
            fv[0] = bf2f(b.x); fv[1] = bf2f(b.y); fv[2] = bf2f(b.z); fv[3] = bf2f(b.w);
            #pragma unroll
            for (int i = 0; i < 4; ++i)
                #pragma unroll
                for (int j = 0; j < 4; ++j) c[i][j] += wv[i] * fv[j];
            if (di == 0) {
                #pragma unroll
                for (int i = 0; i < 4; ++i) nrm[i] += wv[i];
            }
        }
        __syncthreads();
    }
    #pragma unroll
    for (int i = 0; i < 4; ++i)
        #pragma unroll
        for (int j = 0; j < 4; ++j)
            atomicAdd(&tok_raw[(h * 64 + gi * 4 + i) * 64 + di * 4 + j], c[i][j]);
    if (di == 0) {
        #pragma unroll
        for (int i = 0; i < 4; ++i) atomicAdd(&norm[h * 64 + gi * 4 + i], nrm[i]);
    }
}

// ---------------------------------------------------------------------------
// attn: per head, G=64 tokens. 256 threads (4 waves): thread (g=tid&63,
// part=tid>>6) computes 16/64 outputs per matmul stage. Rows hoisted to
// registers; LDS padded [64][65] (2-way alias = free). Weight indices are
// wave-uniform -> scalar loads. All f32.
// ---------------------------------------------------------------------------
__global__ __launch_bounds__(256)
void attn_kernel(const float* __restrict__ tok_raw, const float* __restrict__ norm,
                 const float* __restrict__ Wq, const float* __restrict__ Wk,
                 const float* __restrict__ Wv, const float* __restrict__ Wo,
                 float* __restrict__ out_tok) {
    const int h = blockIdx.x;
    const int tid = threadIdx.x;
    const int g = tid & 63, part = tid >> 6;
    const int o0 = part * 16;

    __shared__ float tk[64][65];
    __shared__ float qq[64][65];
    __shared__ float kk[64][65];
    __shared__ float vv[64][65];
    __shared__ float pp[64][65];
    __shared__ float od[64][65];

    // stage A: tokens = tok_raw / (norm+eps)
    const float inv = 1.f / (norm[h * 64 + g] + EPSF);
    #pragma unroll
    for (int dd = 0; dd < 16; ++dd) {
        int d = o0 + dd;
        tk[g][d] = tok_raw[(size_t)(h * 64 + g) * 64 + d] * inv;
    }
    __syncthreads();

    // stage B: q,k,v (each thread: 16 of 64 outputs)
    float t[64];
    #pragma unroll
    for (int d = 0; d < 64; ++d) t[d] = tk[g][d];
    #pragma unroll
    for (int oo = 0; oo < 16; ++oo) {
        int o = o0 + oo;
        float sq = 0.f, sk = 0.f, sv = 0.f;
        #pragma unroll
        for (int d = 0; d < 64; ++d) {
            float td = t[d];
            sq += td * Wq[o * 64 + d];
            sk += td * Wk[o * 64 + d];
            sv += td * Wv[o * 64 + d];
        }
        qq[g][o] = sq; kk[g][o] = sk; vv[g][o] = sv;
    }
    __syncthreads();

    // stage C: scores s[g][j] for j in part range
    float q[64];
    #pragma unroll
    for (int o = 0; o < 64; ++o) q[o] = qq[g][o];
    #pragma unroll
    for (int jj = 0; jj < 16; ++jj) {
        int j = o0 + jj;
        float s = 0.f;
        #pragma unroll
        for (int o = 0; o < 64; ++o) s += q[o] * kk[j][o];
        pp[g][j] = s * 0.125f;
    }
    __syncthreads();

    // stage D: softmax row (redundant x4 per g — cheap)
    float sr[64];
    float mx = -1e30f;
    #pragma unroll
    for (int j = 0; j < 64; ++j) { sr[j] = pp[g][j]; mx = fmaxf(mx, sr[j]); }
    float sum = 0.f;
    #pragma unroll
    for (int j = 0; j < 64; ++j) { sr[j] = __expf(sr[j] - mx); sum += sr[j]; }
    const float isum = 1.f / sum;

    // stage E: od[g][d] = sum_j p[j] * vv[j][d], d in part range
    #pragma unroll
    for (int dd = 0; dd < 16; ++dd) {
        int d = o0 + dd;
        float a = 0.f;
        #pragma unroll
        for (int j = 0; j < 64; ++j) a += sr[j] * vv[j][d];
        od[g][d] = a * isum;
    }
    __syncthreads();

    // stage F: out[g][o] = sum_d od[g][d] * Wo[o][d], o in part range
    float ot[64];
    #pragma unroll
    for (int d = 0; d < 64; ++d) ot[d] = od[g][d];
    #pragma unroll
    for (int oo = 0; oo < 16; ++oo) {
        int o = o0 + oo;
        float a = 0.f;
        #pragma unroll
        for (int d = 0; d < 64; ++d) a += ot[d] * Wo[o * 64 + d];
        out_tok[(size_t)(h * 64 + g) * 64 + o] = a;
    }
}

// ---------------------------------------------------------------------------
// fold2: V[o, h*64+g] = sum_d out_tok[h,g,d] * Wout[o, h*64+d]  (bf16 out)
// ---------------------------------------------------------------------------
__global__ void fold2_kernel(const float* __restrict__ out_tok,
                             const float* __restrict__ Wout, short* __restrict__ Vbf) {
    int idx = blockIdx.x * 256 + threadIdx.x;
    int o = idx >> 9, hg = idx & 511;
    int h = hg >> 6;
    const float* ot = out_tok + (size_t)hg * 64;
    const float* wo = Wout + (size_t)o * 512 + h * 64;
    float s = 0.f;
    #pragma unroll 8
    for (int d = 0; d < 64; ++d) s += ot[d] * wo[d];
    Vbf[idx] = f2bf(s);
}

// ---------------------------------------------------------------------------
extern "C" void kernel_launch(void* const* d_in, const int* in_sizes, int n_in,
                              void* d_out, int out_size, void* d_ws, size_t ws_size,
                              hipStream_t stream) {
    const float* x    = (const float*)d_in[0];
    const float* Wx   = (const float*)d_in[1];
    const float* bx   = (const float*)d_in[2];
    const float* Wfx  = (const float*)d_in[3];
    const float* bfx  = (const float*)d_in[4];
    const float* Ws   = (const float*)d_in[5];
    const float* bs   = (const float*)d_in[6];
    const float* temp = (const float*)d_in[7];
    const float* Wq   = (const float*)d_in[8];
    const float* Wk   = (const float*)d_in[9];
    const float* Wv   = (const float*)d_in[10];
    const float* Wo   = (const float*)d_in[11];
    const float* Wout = (const float*)d_in[12];
    const float* bout = (const float*)d_in[13];

    const int N = in_sizes[0] / HID;

    char* p = (char*)d_ws;
    short* mid = (short*)p;           p += (size_t)N * 1024 * 2;       // fx | w (bf16)
    short* Wcat = (short*)p;          p += (size_t)1024 * 512 * 2;
    float* bias_cat = (float*)p;      p += 1024 * 4;
    float* tok_raw = (float*)p;       p += (size_t)NH * GG * DD * 4;   // contiguous with norm
    float* norm_ = (float*)p;         p += (size_t)NH * GG * 4;
    float* out_tok = (float*)p;       p += (size_t)NH * GG * DD * 4;
    short* Vbf = (short*)p;           p += (size_t)512 * 512 * 2;
    short* x_bf = (short*)d_out;     // d_out (N*512 f32) hosts x_bf until GEMM2

    cast_kernel<<<(N * 512 / 8 + 255) / 256, 256, 0, stream>>>(x, x_bf, N * 512 / 8);
    fold1_kernel<<<2048, 256, 0, stream>>>(Wx, bx, Wfx, bfx, Ws, bs, temp, Wcat, bias_cat);

    const int R = (N + 127) / 128;
    const int slice = (R + 7) / 8;

    // GEMM1: C=8 col tiles, fused softmax on logits half
    gemm_bt<false, true><<<8 * slice * 8, 256, 0, stream>>>(
        x_bf, HID, Wcat, bias_cat, (void*)mid, 1024, N, 512, 3, R);

    hipMemsetAsync(tok_raw, 0, (size_t)(NH * GG * DD + NH * GG) * 4, stream);

    int chunk = (N + 95) / 96;
    dim3 g2(96, 8);
    pool_kernel<<<g2, 256, 0, stream>>>(mid, tok_raw, norm_, N, chunk);

    attn_kernel<<<8, 256, 0, stream>>>(tok_raw, norm_, Wq, Wk, Wv, Wo, out_tok);

    fold2_kernel<<<1024, 256, 0, stream>>>(out_tok, Wout, Vbf);

    // GEMM2: C=4 col tiles (A = w half of mid, bf16; output f32 + bout)
    gemm_bt<true, false><<<8 * slice * 4, 256, 0, stream>>>(
        mid + 512, 1024, Vbf, bout, d_out, HID, N, 512, 2, R);
}

// Round 5
// 779.767 us; speedup vs baseline: 1.7591x; 1.1363x over previous
//
#include <hip/hip_runtime.h>
#include <hip/hip_bf16.h>

#define HID 512
#define NH  8
#define DD  64
#define GG  64
#define EPSF 1e-5f

typedef __attribute__((ext_vector_type(8))) short short8;
typedef __attribute__((ext_vector_type(4))) short short4v;
typedef __attribute__((ext_vector_type(4))) float floatx4;

__device__ __forceinline__ short f2bf(float f) {
    union { float f; unsigned u; } v; v.f = f;
    unsigned r = v.u + 0x7fffu + ((v.u >> 16) & 1u);
    return (short)(r >> 16);
}
__device__ __forceinline__ float bf2f(short s) {
    union { unsigned u; float f; } v;
    v.u = ((unsigned)(unsigned short)s) << 16;
    return v.f;
}

#define GLOAD_LDS16(g, l) __builtin_amdgcn_global_load_lds( \
    (const __attribute__((address_space(1))) unsigned int*)(g), \
    (__attribute__((address_space(3))) unsigned int*)(l), 16, 0, 0)

// ---------------------------------------------------------------------------
// cast x (f32) -> x_bf (bf16), 8 elems/thread
// ---------------------------------------------------------------------------
__global__ __launch_bounds__(256)
void cast_kernel(const float* __restrict__ x, short* __restrict__ xb, int n8) {
    int i = blockIdx.x * 256 + threadIdx.x;
    if (i >= n8) return;
    const float4* p = (const float4*)(x + (size_t)i * 8);
    float4 a = p[0], b = p[1];
    short8 v;
    v[0] = f2bf(a.x); v[1] = f2bf(a.y); v[2] = f2bf(a.z); v[3] = f2bf(a.w);
    v[4] = f2bf(b.x); v[5] = f2bf(b.y); v[6] = f2bf(b.z); v[7] = f2bf(b.w);
    *(short8*)(xb + (size_t)i * 8) = v;
}

// ---------------------------------------------------------------------------
// fold1: Wcat (1024x512 bf16) = [Wfx ; temp[h] * (Ws @ Wx_head)]
//        bias_cat (1024 f32)  = [bfx ; temp[h] * (Ws @ bx_head + bs)]
// ---------------------------------------------------------------------------
__global__ void fold1_kernel(const float* __restrict__ Wx, const float* __restrict__ bx,
                             const float* __restrict__ Wfx, const float* __restrict__ bfx,
                             const float* __restrict__ Ws, const float* __restrict__ bs,
                             const float* __restrict__ temp,
                             short* __restrict__ Wcat, float* __restrict__ bias_cat) {
    int idx = blockIdx.x * 256 + threadIdx.x;   // 0 .. 1024*512-1
    int row = idx >> 9;
    int k = idx & 511;
    float val;
    if (row < 512) {
        val = Wfx[row * 512 + k];
        if (k == 0) bias_cat[row] = bfx[row];
    } else {
        int hg = row - 512;
        int h = hg >> 6, g = hg & 63;
        float t = temp[h];
        float s = 0.f;
        #pragma unroll 8
        for (int d = 0; d < 64; ++d) s += Ws[g * 64 + d] * Wx[(h * 64 + d) * 512 + k];
        val = s * t;
        if (k == 0) {
            float b = 0.f;
            for (int d = 0; d < 64; ++d) b += Ws[g * 64 + d] * bx[h * 64 + d];
            bias_cat[row] = (b + bs[g]) * t;
        }
    }
    Wcat[idx] = f2bf(val);
}

// ---------------------------------------------------------------------------
// gemm_bt: C(M x ncols) = A(M x K) @ B(ncols x K)^T + bias, bf16 MFMA
// m97 structure: global_load_lds width=16 staging, unpadded LDS stride 32
// shorts with XOR swizzle. 128x128 tile, 4 waves 2x2, 16x16x32 MFMA,
// 4x4/wave. XCD-aware 1-D grid.
// ---------------------------------------------------------------------------
template <bool OUT_F32, bool FUSE_SM>
__global__ __launch_bounds__(256, 4)
void gemm_bt(const short* __restrict__ A, int lda,
             const short* __restrict__ B,           // (ncols x K) bf16 row-major
             const float* __restrict__ bias,
             void* __restrict__ Cp, int ldc,
             int M, int K, int clog2, int Rtiles) {
    __shared__ short As[128 * 32];
    __shared__ short Bs[128 * 32];

    const int id = blockIdx.x;
    const int xcd = id & 7;
    const int s = id >> 3;
    const int cblk = s & ((1 << clog2) - 1);
    const int slice = (Rtiles + 7) >> 3;
    const int rt = xcd * slice + (s >> clog2);
    if (rt >= Rtiles) return;

    const int tid = threadIdx.x;
    const int wid = tid >> 6, lane = tid & 63;
    const int col0 = cblk * 128;
    const int row0 = rt * 128;
    const int wm = (wid >> 1) * 64, wn = (wid & 1) * 64;
    const int lr = lane & 15, lq = lane >> 4;

    int st_row[2], st_kc[2];
    #pragma unroll
    for (int it = 0; it < 2; ++it) {
        int c = tid + it * 256;
        st_row[it] = c >> 2;
        st_kc[it] = (c & 3) ^ ((st_row[it] >> 1) & 3);
    }
    const int fx_ = lq ^ ((lr >> 1) & 3);

    floatx4 acc[4][4];
    #pragma unroll
    for (int i = 0; i < 4; ++i)
        #pragma unroll
        for (int j = 0; j < 4; ++j) acc[i][j] = (floatx4)(0.f);

    const short* Abase = A + (size_t)row0 * lda;
    const short* Bbase = B + (size_t)col0 * lda;

    for (int k0 = 0; k0 < K; k0 += 32) {
        #pragma unroll
        for (int it = 0; it < 2; ++it) {
            short* ldsA = As + (wid * 64 + it * 256) * 8;
            short* ldsB = Bs + (wid * 64 + it * 256) * 8;
            GLOAD_LDS16(Abase + (size_t)st_row[it] * lda + k0 + st_kc[it] * 8, ldsA);
            GLOAD_LDS16(Bbase + (size_t)st_row[it] * lda + k0 + st_kc[it] * 8, ldsB);
        }
        __syncthreads();

        short8 af[4], bfr[4];
        #pragma unroll
        for (int i = 0; i < 4; ++i) af[i]  = *(const short8*)&As[(wm + i * 16 + lr) * 32 + fx_ * 8];
        #pragma unroll
        for (int j = 0; j < 4; ++j) bfr[j] = *(const short8*)&Bs[(wn + j * 16 + lr) * 32 + fx_ * 8];
        #pragma unroll
        for (int i = 0; i < 4; ++i)
            #pragma unroll
            for (int j = 0; j < 4; ++j)
                acc[i][j] = __builtin_amdgcn_mfma_f32_16x16x32_bf16(af[i], bfr[j], acc[i][j], 0, 0, 0);
        __syncthreads();
    }

    const bool do_sm = FUSE_SM && (col0 >= 512);
    float bcol[4];
    #pragma unroll
    for (int j = 0; j < 4; ++j) bcol[j] = bias[col0 + wn + j * 16 + lr];

    #pragma unroll
    for (int i = 0; i < 4; ++i) {
        #pragma unroll
        for (int r = 0; r < 4; ++r) {
            int grow = row0 + wm + i * 16 + lq * 4 + r;
            float v[4];
            #pragma unroll
            for (int j = 0; j < 4; ++j) v[j] = acc[i][j][r] + bcol[j];
            if (do_sm) {
                float m = fmaxf(fmaxf(v[0], v[1]), fmaxf(v[2], v[3]));
                #pragma unroll
                for (int off = 1; off < 16; off <<= 1) m = fmaxf(m, __shfl_xor(m, off));
                float sum = 0.f;
                #pragma unroll
                for (int j = 0; j < 4; ++j) { v[j] = __expf(v[j] - m); sum += v[j]; }
                #pragma unroll
                for (int off = 1; off < 16; off <<= 1) sum += __shfl_xor(sum, off);
                float inv = 1.f / sum;
                #pragma unroll
                for (int j = 0; j < 4; ++j) v[j] *= inv;
            }
            if (grow < M) {
                #pragma unroll
                for (int j = 0; j < 4; ++j) {
                    int gcol = col0 + wn + j * 16 + lr;
                    if constexpr (OUT_F32) ((float*)Cp)[(size_t)grow * ldc + gcol] = v[j];
                    else                   ((short*)Cp)[(size_t)grow * ldc + gcol] = f2bf(v[j]);
                }
            }
        }
    }
}

// ---------------------------------------------------------------------------
// pool_mfma: tok_raw[h,g,d] += sum_n w[n,h,g]*fx[n,h,d]; norm[h,g] += sum_n w
// MFMA formulation ("TN" gemm): stage 32n x 64c tiles row-major, fill frags
// with per-lane ds_read_u16 (transposed read). LDS stride 72 shorts (16B
// aligned for b128 staging) + 16-col rotation per 8-row group -> frag reads
// land 2 lanes/bank (free). Waves tile 2x2 over (g,d); norm via a constant
// all-ones B-frag MFMA. Split-K over grid.x, f32 atomicAdd epilogue.
// chunk must be a multiple of 32; N % 32 == 0.
// ---------------------------------------------------------------------------
__global__ __launch_bounds__(256)
void pool_mfma(const short* __restrict__ mid, float* __restrict__ tok_raw,
               float* __restrict__ norm, int N, int chunk) {
    const int h = blockIdx.y;
    const int n0 = blockIdx.x * chunk;
    if (n0 >= N) return;
    const int ksteps = (min(chunk, N - n0)) >> 5;

    const int tid = threadIdx.x;
    const int wid = tid >> 6, lane = tid & 63;
    const int lr = lane & 15, lq = lane >> 4;
    const int wg = (wid >> 1) * 32, wd = (wid & 1) * 32;

    __shared__ short wt[32 * 72];
    __shared__ short ft[32 * 72];

    // staging: thread -> row n = tid>>3 (0..31), col chunk c0 = (tid&7)*8
    const int sn = tid >> 3;
    const int sc0 = (tid & 7) * 8;
    const int scr = (sc0 + 16 * ((sn >> 3) & 3)) & 63;   // rotated col
    const int st_off = sn * 72 + scr;

    // frag reads: row k = lq*8+j, col (c + 16*lq) & 63
    const int ra = ((wg + lr) + 16 * lq) & 63;           // A cols (i adds 16)
    const int rb = ((wd + lr) + 16 * lq) & 63;           // B cols (j adds 16)

    const short* wbase = mid + (size_t)n0 * 1024 + 512 + h * 64;
    const short* fbase = mid + (size_t)n0 * 1024 + h * 64;

    floatx4 acc[2][2];
    #pragma unroll
    for (int i = 0; i < 2; ++i)
        #pragma unroll
        for (int j = 0; j < 2; ++j) acc[i][j] = (floatx4)(0.f);
    floatx4 accn[2];
    accn[0] = (floatx4)(0.f); accn[1] = (floatx4)(0.f);

    short8 ones;
    #pragma unroll
    for (int j = 0; j < 8; ++j) ones[j] = (short)0x3F80;   // bf16 1.0

    for (int ks = 0; ks < ksteps; ++ks) {
        const size_t roff = (size_t)(ks * 32 + sn) * 1024;
        short8 wv = *(const short8*)(wbase + roff + sc0);
        short8 fv = *(const short8*)(fbase + roff + sc0);
        __syncthreads();                 // previous iter's frag reads done
        *(short8*)&wt[st_off] = wv;
        *(short8*)&ft[st_off] = fv;
        __syncthreads();

        short8 af[2], bf_[2];
        #pragma unroll
        for (int i = 0; i < 2; ++i) {
            short tmpv[8];
            #pragma unroll
            for (int j = 0; j < 8; ++j)
                tmpv[j] = wt[(lq * 8 + j) * 72 + ((ra + i * 16) & 63)];
            af[i] = *(const short8*)tmpv;
        }
        #pragma unroll
        for (int j2 = 0; j2 < 2; ++j2) {
            short tmpv[8];
            #pragma unroll
            for (int j = 0; j < 8; ++j)
                tmpv[j] = ft[(lq * 8 + j) * 72 + ((rb + j2 * 16) & 63)];
            bf_[j2] = *(const short8*)tmpv;
        }
        #pragma unroll
        for (int i = 0; i < 2; ++i)
            #pragma unroll
            for (int j = 0; j < 2; ++j)
                acc[i][j] = __builtin_amdgcn_mfma_f32_16x16x32_bf16(af[i], bf_[j], acc[i][j], 0, 0, 0);
        if (wd == 0) {
            #pragma unroll
            for (int i = 0; i < 2; ++i)
                accn[i] = __builtin_amdgcn_mfma_f32_16x16x32_bf16(af[i], ones, accn[i], 0, 0, 0);
        }
    }

    // epilogue: D col = lane&15, row = lq*4 + r
    #pragma unroll
    for (int i = 0; i < 2; ++i) {
        #pragma unroll
        for (int r = 0; r < 4; ++r) {
            int g = wg + i * 16 + lq * 4 + r;
            #pragma unroll
            for (int j = 0; j < 2; ++j) {
                int d = wd + j * 16 + lr;
                atomicAdd(&tok_raw[(h * 64 + g) * 64 + d], acc[i][j][r]);
            }
        }
    }
    if (wd == 0 && lr == 0) {
        #pragma unroll
        for (int i = 0; i < 2; ++i)
            #pragma unroll
            for (int r = 0; r < 4; ++r)
                atomicAdd(&norm[h * 64 + wg + i * 16 + lq * 4 + r], accn[i][r]);
    }
}

// ---------------------------------------------------------------------------
// attn: per head, G=64 tokens. 256 threads (4 waves): thread (g=tid&63,
// part=tid>>6) computes 16/64 outputs per matmul stage. All f32.
// ---------------------------------------------------------------------------
__global__ __launch_bounds__(256)
void attn_kernel(const float* __restrict__ tok_raw, const float* __restrict__ norm,
                 const float* __restrict__ Wq, const float* __restrict__ Wk,
                 const float* __restrict__ Wv, const float* __restrict__ Wo,
                 float* __restrict__ out_tok) {
    const int h = blockIdx.x;
    const int tid = threadIdx.x;
    const int g = tid & 63, part = tid >> 6;
    const int o0 = part * 16;

    __shared__ float tk[64][65];
    __shared__ float qq[64][65];
    __shared__ float kk[64][65];
    __shared__ float vv[64][65];
    __shared__ float pp[64][65];
    __shared__ float od[64][65];

    const float inv = 1.f / (norm[h * 64 + g] + EPSF);
    #pragma unroll
    for (int dd = 0; dd < 16; ++dd) {
        int d = o0 + dd;
        tk[g][d] = tok_raw[(size_t)(h * 64 + g) * 64 + d] * inv;
    }
    __syncthreads();

    float t[64];
    #pragma unroll
    for (int d = 0; d < 64; ++d) t[d] = tk[g][d];
    #pragma unroll
    for (int oo = 0; oo < 16; ++oo) {
        int o = o0 + oo;
        float sq = 0.f, sk = 0.f, sv = 0.f;
        #pragma unroll
        for (int d = 0; d < 64; ++d) {
            float td = t[d];
            sq += td * Wq[o * 64 + d];
            sk += td * Wk[o * 64 + d];
            sv += td * Wv[o * 64 + d];
        }
        qq[g][o] = sq; kk[g][o] = sk; vv[g][o] = sv;
    }
    __syncthreads();

    float q[64];
    #pragma unroll
    for (int o = 0; o < 64; ++o) q[o] = qq[g][o];
    #pragma unroll
    for (int jj = 0; jj < 16; ++jj) {
        int j = o0 + jj;
        float s = 0.f;
        #pragma unroll
        for (int o = 0; o < 64; ++o) s += q[o] * kk[j][o];
        pp[g][j] = s * 0.125f;
    }
    __syncthreads();

    float sr[64];
    float mx = -1e30f;
    #pragma unroll
    for (int j = 0; j < 64; ++j) { sr[j] = pp[g][j]; mx = fmaxf(mx, sr[j]); }
    float sum = 0.f;
    #pragma unroll
    for (int j = 0; j < 64; ++j) { sr[j] = __expf(sr[j] - mx); sum += sr[j]; }
    const float isum = 1.f / sum;

    #pragma unroll
    for (int dd = 0; dd < 16; ++dd) {
        int d = o0 + dd;
        float a = 0.f;
        #pragma unroll
        for (int j = 0; j < 64; ++j) a += sr[j] * vv[j][d];
        od[g][d] = a * isum;
    }
    __syncthreads();

    float ot[64];
    #pragma unroll
    for (int d = 0; d < 64; ++d) ot[d] = od[g][d];
    #pragma unroll
    for (int oo = 0; oo < 16; ++oo) {
        int o = o0 + oo;
        float a = 0.f;
        #pragma unroll
        for (int d = 0; d < 64; ++d) a += ot[d] * Wo[o * 64 + d];
        out_tok[(size_t)(h * 64 + g) * 64 + o] = a;
    }
}

// ---------------------------------------------------------------------------
// fold2: V[o, h*64+g] = sum_d out_tok[h,g,d] * Wout[o, h*64+d]  (bf16 out)
// ---------------------------------------------------------------------------
__global__ void fold2_kernel(const float* __restrict__ out_tok,
                             const float* __restrict__ Wout, short* __restrict__ Vbf) {
    int idx = blockIdx.x * 256 + threadIdx.x;
    int o = idx >> 9, hg = idx & 511;
    int h = hg >> 6;
    const float* ot = out_tok + (size_t)hg * 64;
    const float* wo = Wout + (size_t)o * 512 + h * 64;
    float s = 0.f;
    #pragma unroll 8
    for (int d = 0; d < 64; ++d) s += ot[d] * wo[d];
    Vbf[idx] = f2bf(s);
}

// ---------------------------------------------------------------------------
extern "C" void kernel_launch(void* const* d_in, const int* in_sizes, int n_in,
                              void* d_out, int out_size, void* d_ws, size_t ws_size,
                              hipStream_t stream) {
    const float* x    = (const float*)d_in[0];
    const float* Wx   = (const float*)d_in[1];
    const float* bx   = (const float*)d_in[2];
    const float* Wfx  = (const float*)d_in[3];
    const float* bfx  = (const float*)d_in[4];
    const float* Ws   = (const float*)d_in[5];
    const float* bs   = (const float*)d_in[6];
    const float* temp = (const float*)d_in[7];
    const float* Wq   = (const float*)d_in[8];
    const float* Wk   = (const float*)d_in[9];
    const float* Wv   = (const float*)d_in[10];
    const float* Wo   = (const float*)d_in[11];
    const float* Wout = (const float*)d_in[12];
    const float* bout = (const float*)d_in[13];

    const int N = in_sizes[0] / HID;

    char* p = (char*)d_ws;
    short* mid = (short*)p;           p += (size_t)N * 1024 * 2;       // fx | w (bf16)
    short* Wcat = (short*)p;          p += (size_t)1024 * 512 * 2;
    float* bias_cat = (float*)p;      p += 1024 * 4;
    float* tok_raw = (float*)p;       p += (size_t)NH * GG * DD * 4;   // contiguous with norm
    float* norm_ = (float*)p;         p += (size_t)NH * GG * 4;
    float* out_tok = (float*)p;       p += (size_t)NH * GG * DD * 4;
    short* Vbf = (short*)p;           p += (size_t)512 * 512 * 2;
    short* x_bf = (short*)d_out;     // d_out (N*512 f32) hosts x_bf until GEMM2

    cast_kernel<<<(N * 512 / 8 + 255) / 256, 256, 0, stream>>>(x, x_bf, N * 512 / 8);
    fold1_kernel<<<2048, 256, 0, stream>>>(Wx, bx, Wfx, bfx, Ws, bs, temp, Wcat, bias_cat);

    const int R = (N + 127) / 128;
    const int slice = (R + 7) / 8;

    // GEMM1: C=8 col tiles, fused softmax on logits half
    gemm_bt<false, true><<<8 * slice * 8, 256, 0, stream>>>(
        x_bf, HID, Wcat, bias_cat, (void*)mid, 1024, N, 512, 3, R);

    hipMemsetAsync(tok_raw, 0, (size_t)(NH * GG * DD + NH * GG) * 4, stream);

    // pool: split-K MFMA; chunk multiple of 32 (N=100000 is a multiple of 32)
    const int chunk = 544;                       // 17 k-steps per block
    dim3 g2((N + chunk - 1) / chunk, 8);
    pool_mfma<<<g2, 256, 0, stream>>>(mid, tok_raw, norm_, N, chunk);

    attn_kernel<<<8, 256, 0, stream>>>(tok_raw, norm_, Wq, Wk, Wv, Wo, out_tok);

    fold2_kernel<<<1024, 256, 0, stream>>>(out_tok, Wout, Vbf);

    // GEMM2: C=4 col tiles (A = w half of mid, bf16; output f32 + bout)
    gemm_bt<true, false><<<8 * slice * 4, 256, 0, stream>>>(
        mid + 512, 1024, Vbf, bout, d_out, HID, N, 512, 2, R);
}